// Round 2
// baseline (1393.886 us; speedup 1.0000x reference)
//
#include <hip/hip_runtime.h>
#include <math.h>

// ---------------------------------------------------------------------------
// VQ-VAE forward, B=4096. Scalar f32 loss in d_out[0].
//
// ws float layout:
//   wt2g  @ 0      : 18432   conv2 W    [(ci*9+k)*64 + co]
//   wt1g  @ 18432  : 32768   convT1 W   [(ci*16+k)*32 + co]
//   wtd2g @ 51200  : 1536    convT2 W   [(ci*16+k)*3 + co]
//   embtg @ 52736  : 4096    emb^T      [d*64 + k]
//   w1tg  @ 56832  : 864     conv1 W    [(ci*9+k)*32 + co]
//   tokens @ byte 230912     : 4096*64 uchar
// ---------------------------------------------------------------------------

__global__ __launch_bounds__(256) void k_init(
    const float* __restrict__ w1, const float* __restrict__ w2,
    const float* __restrict__ wd1, const float* __restrict__ wd2,
    const float* __restrict__ emb, float* __restrict__ ws,
    float* __restrict__ out)
{
  int gid = blockIdx.x * 256 + threadIdx.x;
  if (gid == 0) out[0] = 0.f;
  if (gid < 32768) {                       // wd1: (64ci,32co,4,4) -> [(ci*16+k)*32+co]
    int ci = gid >> 9, co = (gid >> 4) & 31, k = gid & 15;
    ws[18432 + (ci*16 + k)*32 + co] = wd1[gid];
  }
  if (gid < 18432) {                       // w2: (64co,32ci,3,3) -> [(ci*9+k)*64+co]
    int co = gid / 288, j = gid - co*288;
    ws[j*64 + co] = w2[gid];
  }
  if (gid < 4096) {                        // emb: (64k,64d) -> [d*64+k]
    int k = gid >> 6, d = gid & 63;
    ws[52736 + d*64 + k] = emb[gid];
  }
  if (gid < 1536) {                        // wd2: (32ci,3co,4,4) -> [(ci*16+k)*3+co]
    int ci = gid / 48, r = gid - ci*48, co = r >> 4, k = r & 15;
    ws[51200 + (ci*16 + k)*3 + co] = wd2[gid];
  }
  if (gid < 864) {                         // w1: (32co,3ci,3,3) -> [(ci*9+k)*32+co]
    int co = gid / 27, j = gid - co*27;
    ws[56832 + j*32 + co] = w1[gid];
  }
}

// ---------------------------------------------------------------------------
// k123: per image: conv1+ReLU -> conv2 -> VQ argmin. Emits uint8 tokens and
// (1+beta)*sum||e - x_enc|| loss term. One block per image, 256 threads.
// ---------------------------------------------------------------------------
__global__ __launch_bounds__(256) void k123(
    const float* __restrict__ x,
    const float* __restrict__ b1v, const float* __restrict__ b2v,
    const float* __restrict__ emb,
    const float* __restrict__ ws,
    unsigned char* __restrict__ tokens,
    float* __restrict__ loss)
{
  __shared__ __align__(16) float smem[13320];
  float* h1s   = smem;           // [32][16][18] (conv1 out, pad-18 rows)
  float* xt    = smem + 9216;    // [3][34][34]  (bordered x tile)
  float* xe    = smem + 9216;    // [64][64] swizzled x_enc (aliases xt)
  float* enat  = smem;           // [64][68] emb natural (aliases h1s)
  float* norms = smem + 4352;    // 64
  float* red   = smem + 13312;   // 8

  const int tid = threadIdx.x;
  const int b = blockIdx.x;
  const float* w1tg = ws + 56832;
  const float* wt2g = ws;

  // stage x tile with zero border
  for (int i = tid; i < 3468; i += 256) xt[i] = 0.f;
  __syncthreads();
  for (int i = tid; i < 3072; i += 256) {
    int ci = i >> 10, rr = (i >> 5) & 31, cc = i & 31;
    xt[ci*1156 + (rr+1)*34 + (cc+1)] = x[b*3072 + i];
  }
  __syncthreads();

  // ---- conv1 (3->32, k3 s2 p1) + ReLU ----
  {
    const int cs = tid >> 6;     // co = cs*8+q
    const int l  = tid & 63;
    float acc[4][8];
#pragma unroll
    for (int i=0;i<4;i++)
#pragma unroll
      for (int q=0;q<8;q++) acc[i][q]=0.f;
#pragma unroll
    for (int ci=0; ci<3; ci++)
#pragma unroll
      for (int kh=0; kh<3; kh++)
#pragma unroll
        for (int kw=0; kw<3; kw++) {
          const float* wp = &w1tg[(ci*9 + kh*3 + kw)*32 + cs*8];
          float w0=wp[0],w1_=wp[1],w2_=wp[2],w3=wp[3],w4=wp[4],w5=wp[5],w6=wp[6],w7=wp[7];
#pragma unroll
          for (int i=0;i<4;i++) {
            int sp = i*64 + l;
            int oh = sp >> 4, ow = sp & 15;
            // ih = 2*oh-1+kh ; bordered index = ih+1 = 2*oh+kh
            float xv = xt[ci*1156 + (2*oh + kh)*34 + (2*ow + kw)];
            acc[i][0] += w0*xv; acc[i][1] += w1_*xv; acc[i][2] += w2_*xv; acc[i][3] += w3*xv;
            acc[i][4] += w4*xv; acc[i][5] += w5*xv; acc[i][6] += w6*xv; acc[i][7] += w7*xv;
          }
        }
#pragma unroll
    for (int q=0;q<8;q++) {
      float bias = b1v[cs*8+q];
#pragma unroll
      for (int i=0;i<4;i++) {
        int sp = i*64+l;
        int oh = sp>>4, ow = sp&15;
        float v = acc[i][q] + bias;
        h1s[(cs*8+q)*288 + oh*18 + ow] = v > 0.f ? v : 0.f;
      }
    }
  }
  __syncthreads();

  // ---- conv2 (32->64, k3 s2 p1) + bias -> xe (token-major, swizzled) ----
  {
    const int cg = tid >> 6;     // co = cg*16+q
    const int l = tid & 63;
    const int t = l & 31;        // handles tokens t and t+32 (same h, w+4)
    const int h = t & 7, w = t >> 3;
    float acc0[16], acc1[16];
#pragma unroll
    for (int q=0;q<16;q++){acc0[q]=0.f;acc1[q]=0.f;}
    for (int ci=0; ci<32; ci++) {
#pragma unroll
      for (int kh=0; kh<3; kh++) {
        int ih = 2*h - 1 + kh;               // [-1,15]
        bool ihok = (ih >= 0);
        const float* hp = &h1s[ci*288 + ih*18];
#pragma unroll
        for (int kw=0; kw<3; kw++) {
          int iw = 2*w - 1 + kw;             // [-1,8]
          float v1 = (ihok && iw >= 0) ? hp[iw]   : 0.f;  // token t   (iw<=8<16 ok)
          float v2 = (ihok && iw < 8)  ? hp[iw+8] : 0.f;  // token t+32 (iw+8<=15)
          const float4* wp = (const float4*)&wt2g[(ci*9 + kh*3 + kw)*64 + cg*16];
          float wv[16];
          *(float4*)&wv[0]  = wp[0];
          *(float4*)&wv[4]  = wp[1];
          *(float4*)&wv[8]  = wp[2];
          *(float4*)&wv[12] = wp[3];
#pragma unroll
          for (int q=0;q<16;q++) { acc0[q] += wv[q]*v1; acc1[q] += wv[q]*v2; }
        }
      }
    }
    const int t2 = t + 32;
#pragma unroll
    for (int q=0;q<16;q++) {
      int d = cg*16 + q;
      float bias = b2v[d];
      xe[t *64 + ((d + t )&63)] = acc0[q] + bias;
      xe[t2*64 + ((d + t2)&63)] = acc1[q] + bias;
    }
  }
  __syncthreads();

  // ---- stage emb (natural layout) + code norms ----
  for (int i = tid; i < 4096; i += 256) {
    int k = i >> 6, d = i & 63;
    enat[k*68 + d] = emb[i];
  }
  __syncthreads();
  if (tid < 64) {
    float s = 0.f;
    for (int j=0;j<64;j++){ float e = enat[tid*68+j]; s += e*e; }
    norms[tid] = s;
  }
  __syncthreads();

  // ---- VQ: argmin_k (||c_k||^2 - 2 x.c_k), 4 lanes per token ----
  {
    const int dq = tid & 3;
    const int t = tid >> 2;
    float xq[16];
#pragma unroll
    for (int j=0;j<16;j++) {
      int d = dq*16 + j;
      xq[j] = xe[t*64 + ((d + t)&63)];
    }
    float best = 3.4e38f; int bestk = 0;
    for (int k=0;k<64;k++) {
      const float4* ep = (const float4*)&enat[k*68 + dq*16];
      float dot = 0.f;
#pragma unroll
      for (int u=0;u<4;u++) {
        float4 e4 = ep[u];
        dot += e4.x*xq[u*4+0] + e4.y*xq[u*4+1] + e4.z*xq[u*4+2] + e4.w*xq[u*4+3];
      }
      dot += __shfl_xor(dot, 1);
      dot += __shfl_xor(dot, 2);
      float score = norms[k] - 2.f*dot;
      if (score < best) { best = score; bestk = k; }
    }
    const float4* ep = (const float4*)&enat[bestk*68 + dq*16];
    float d2 = 0.f;
#pragma unroll
    for (int u=0;u<4;u++) {
      float4 e4 = ep[u];
      float a0 = e4.x - xq[u*4+0], a1 = e4.y - xq[u*4+1];
      float a2 = e4.z - xq[u*4+2], a3 = e4.w - xq[u*4+3];
      d2 += a0*a0 + a1*a1 + a2*a2 + a3*a3;
    }
    d2 += __shfl_xor(d2, 1);
    d2 += __shfl_xor(d2, 2);
    float val = 0.f;
    if (dq == 0) {
      tokens[b*64 + t] = (unsigned char)bestk;
      val = sqrtf(d2);
    }
#pragma unroll
    for (int off=1; off<64; off<<=1) val += __shfl_xor(val, off);
    if ((tid & 63) == 0) red[tid>>6] = val;
    __syncthreads();
    if (tid == 0) atomicAdd(loss, (red[0]+red[1]+red[2]+red[3]) * (1.1f/4096.f));
  }
}

// ---------------------------------------------------------------------------
// k45: per image: convT1(64->32,k4,s2,p1)+ReLU -> convT2(32->3) fused with
// recon loss. Decoder input gathered as emb_t[ci][token] (vq never stored).
// ---------------------------------------------------------------------------
__global__ __launch_bounds__(256) void k45(
    const float* __restrict__ x,
    const float* __restrict__ bd1v, const float* __restrict__ bd2v,
    const float* __restrict__ ws,
    const unsigned char* __restrict__ tokens,
    float* __restrict__ loss)
{
  __shared__ __align__(16) float smem[14792];
  float* embts = smem;              // [64][68], col 64 == 0 (invalid-tap sink)
  float* wtd2s = smem;              // phase-B alias (1536)
  int*   tok_s = (int*)(smem + 4352);  // 64
  float* dl    = smem + 4416;       // [32][18][18] bordered, zero ring
  float* red   = smem + 14784;

  const int tid = threadIdx.x;
  const int b = blockIdx.x;
  const float4* wt1v = (const float4*)(ws + 18432);
  const float* wtd2g = ws + 51200;
  const float* embtg = ws + 52736;

  for (int i = tid; i < 4096; i += 256) {
    int d = i >> 6, k = i & 63;
    embts[d*68 + k] = embtg[i];
  }
  if (tid < 64) {
    embts[tid*68 + 64] = 0.f;
    tok_s[tid] = tokens[b*64 + tid];
  }
  for (int i = tid; i < 10368; i += 256) dl[i] = 0.f;
  __syncthreads();

  // ---- convT1 + ReLU -> dl ----
  {
    const int cb = tid & 7;          // co = cb*4+q
    const int sg = tid >> 3;
    const int i0 = sg >> 2;          // quarter-grid row
    const int j0 = (sg & 3) * 2;     // quarter-grid col pair base
    int off[12];                     // 3 rows x 4 cols of tokens (64 = zero col)
#pragma unroll
    for (int rr=0; rr<3; rr++)
#pragma unroll
      for (int cc=0; cc<4; cc++) {
        int ih = i0 - 1 + rr, iw = j0 - 1 + cc;
        off[rr*4+cc] = (ih>=0 && ih<8 && iw>=0 && iw<8) ? tok_s[iw*8+ih] : 64;
      }
    float acc[4][2][4];
#pragma unroll
    for (int p=0;p<4;p++)
#pragma unroll
      for (int s=0;s<2;s++)
#pragma unroll
        for (int q=0;q<4;q++) acc[p][s][q]=0.f;

    for (int ci=0; ci<64; ci++) {
      float v[12];
#pragma unroll
      for (int m=0;m<12;m++) v[m] = embts[ci*68 + off[m]];
#pragma unroll
      for (int r=0;r<2;r++)
#pragma unroll
        for (int c=0;c<2;c++) {
          // parity (r,c): taps (kh,kw) uniform per parity
          const int kh0 = r ? 2 : 1, kh1 = r ? 0 : 3;
          const int r0 = 1,          r1 = r ? 2 : 0;
          const int kw0 = c ? 2 : 1, kw1 = c ? 0 : 3;
          const int c0 = 1,          c1 = c ? 2 : 0;
          float4 w00 = wt1v[(ci*16 + kh0*4+kw0)*8 + cb];
          float4 w01 = wt1v[(ci*16 + kh0*4+kw1)*8 + cb];
          float4 w10 = wt1v[(ci*16 + kh1*4+kw0)*8 + cb];
          float4 w11 = wt1v[(ci*16 + kh1*4+kw1)*8 + cb];
          const int par = r*2+c;
#pragma unroll
          for (int s=0;s<2;s++) {
            float v00 = v[r0*4 + c0 + s];
            float v01 = v[r0*4 + c1 + s];
            float v10 = v[r1*4 + c0 + s];
            float v11 = v[r1*4 + c1 + s];
            acc[par][s][0] += v00*w00.x + v01*w01.x + v10*w10.x + v11*w11.x;
            acc[par][s][1] += v00*w00.y + v01*w01.y + v10*w10.y + v11*w11.y;
            acc[par][s][2] += v00*w00.z + v01*w01.z + v10*w10.z + v11*w11.z;
            acc[par][s][3] += v00*w00.w + v01*w01.w + v10*w10.w + v11*w11.w;
          }
        }
    }
#pragma unroll
    for (int r=0;r<2;r++)
#pragma unroll
      for (int c=0;c<2;c++)
#pragma unroll
        for (int s=0;s<2;s++)
#pragma unroll
          for (int q=0;q<4;q++) {
            int co = cb*4 + q;
            int oh = 2*i0 + r, ow = 2*(j0+s) + c;
            float vv = acc[r*2+c][s][q] + bd1v[co];
            dl[co*324 + (oh+1)*18 + (ow+1)] = vv > 0.f ? vv : 0.f;
          }
  }
  __syncthreads();
  for (int i = tid; i < 1536; i += 256) wtd2s[i] = wtd2g[i];
  __syncthreads();

  // ---- convT2 + recon loss ----
  {
    const int oh = tid >> 3;           // [0,32)
    const int ow0 = (tid & 7) * 4;     // 4 consecutive cols
    const int p_h = (oh + 1) & 1;
    const int ihh = (oh + 1) >> 1;
    const int iwb = ow0 >> 1;
    float acc[3][4];
#pragma unroll
    for (int co=0;co<3;co++)
#pragma unroll
      for (int u=0;u<4;u++) acc[co][u]=0.f;

    for (int ci=0; ci<32; ci++) {
      float v[2][4];
#pragma unroll
      for (int dh=0; dh<2; dh++)
#pragma unroll
        for (int cc=0; cc<4; cc++) {
          int ih = ihh - dh;           // [-1,16] -> border
          int iw = iwb - 1 + cc;       // [-1,16] -> border
          v[dh][cc] = dl[ci*324 + (ih+1)*18 + (iw+1)];
        }
      float wv[3][2][2][2];
#pragma unroll
      for (int co=0;co<3;co++)
#pragma unroll
        for (int dh=0;dh<2;dh++)
#pragma unroll
          for (int pu=0;pu<2;pu++)
#pragma unroll
            for (int dw=0;dw<2;dw++)
              wv[co][dh][pu][dw] = wtd2s[(ci*16 + (p_h + 2*dh)*4 + (pu + 2*dw))*3 + co];
#pragma unroll
      for (int u=0;u<4;u++) {
        const int pu = (u+1)&1;
        const int cb_ = ((u+1)>>1) + 1;
#pragma unroll
        for (int dh=0;dh<2;dh++)
#pragma unroll
          for (int dw=0;dw<2;dw++) {
            float vv = v[dh][cb_ - dw];
            acc[0][u] += vv * wv[0][dh][pu][dw];
            acc[1][u] += vv * wv[1][dh][pu][dw];
            acc[2][u] += vv * wv[2][dh][pu][dw];
          }
      }
    }
    float lsum = 0.f;
#pragma unroll
    for (int co=0;co<3;co++) {
      float4 xv = *(const float4*)&x[b*3072 + co*1024 + oh*32 + ow0];
      float bias = bd2v[co];
      float e0 = xv.x - (acc[co][0]+bias);
      float e1 = xv.y - (acc[co][1]+bias);
      float e2 = xv.z - (acc[co][2]+bias);
      float e3 = xv.w - (acc[co][3]+bias);
      lsum += e0*e0 + e1*e1 + e2*e2 + e3*e3;
    }
#pragma unroll
    for (int off=1; off<64; off<<=1) lsum += __shfl_xor(lsum, off);
    if ((tid & 63) == 0) red[tid>>6] = lsum;
    __syncthreads();
    if (tid == 0) atomicAdd(loss, (red[0]+red[1]+red[2]+red[3]) * (0.5f/4096.f));
  }
}

extern "C" void kernel_launch(void* const* d_in, const int* in_sizes, int n_in,
                              void* d_out, int out_size, void* d_ws, size_t ws_size,
                              hipStream_t stream) {
  const float* x   = (const float*)d_in[0];
  const float* w1  = (const float*)d_in[1];
  const float* b1  = (const float*)d_in[2];
  const float* w2  = (const float*)d_in[3];
  const float* b2  = (const float*)d_in[4];
  const float* wd1 = (const float*)d_in[5];
  const float* bd1 = (const float*)d_in[6];
  const float* wd2 = (const float*)d_in[7];
  const float* bd2 = (const float*)d_in[8];
  const float* emb = (const float*)d_in[9];
  float* out = (float*)d_out;
  float* ws  = (float*)d_ws;
  unsigned char* tokens = (unsigned char*)d_ws + 230912;

  k_init<<<128, 256, 0, stream>>>(w1, w2, wd1, wd2, emb, ws, out);
  k123<<<4096, 256, 0, stream>>>(x, b1, b2, emb, ws, tokens, out);
  k45<<<4096, 256, 0, stream>>>(x, bd1, bd2, ws, tokens, out);
}